// Round 12
// baseline (235.024 us; speedup 1.0000x reference)
//
#include <hip/hip_runtime.h>
#include <hip/hip_bf16.h>

// GraphReconstructionGCN: N=50000, E=800000, GCN 128 -> 128 -> 64.
// Round 12: gather_l2 split into TWO launches sharded by SRC ROW RANGE (not
// columns -- r10 proved fetch granularity is 256B, so column splits are free-
// fetch; row-range shards shrink the line working set: 3.2MB < 4MiB/XCD L2).
// Cross-pass partial accumulator (64 f32/node, 12.8MB) aliases the dead agg1
// buffer -- no ws growth, full f32 precision. Launch boundaries supply the
// temporal phase alignment r9's in-kernel barrier could not (and cost nothing).
static constexpr int FIN   = 128;
static constexpr int FHID  = 128;
static constexpr int FOUTC = 64;
static constexpr int CAP   = 64;  // hash slots per node

typedef short bf16x8 __attribute__((ext_vector_type(8)));
typedef float f32x4 __attribute__((ext_vector_type(4)));
typedef unsigned u32x2 __attribute__((ext_vector_type(2)));
typedef unsigned u32x4 __attribute__((ext_vector_type(4)));

__device__ __forceinline__ float bfbits2f(unsigned short u) {
  union { unsigned i; float f; } c; c.i = ((unsigned)u) << 16; return c.f;
}
__device__ __forceinline__ float wbits2f(unsigned u) {
  union { unsigned i; float f; } c; c.i = u; return c.f;
}
__device__ __forceinline__ unsigned f2wbits(float f) {
  union { float fv; unsigned i; } c; c.fv = f; return c.i;
}
__device__ __forceinline__ void unpack_bf2(unsigned u, float& lo, float& hi) {
  union { unsigned i; float f; } a, b;
  a.i = u << 16;
  b.i = u & 0xffff0000u;
  lo = a.f; hi = b.f;
}
__device__ __forceinline__ unsigned short f2bfbits(float f) {
  union { float fv; unsigned i; } c; c.fv = f;
  unsigned i = c.i;
  unsigned r = i + 0x7FFFu + ((i >> 16) & 1u);  // RNE
  if ((i & 0x7F800000u) == 0x7F800000u) r = i;  // inf/nan passthrough
  return (unsigned short)(r >> 16);
}
__device__ __forceinline__ int ld_idx(const void* ei, int is64, long long off) {
  return is64 ? (int)((const long long*)ei)[off] : ((const int*)ei)[off];
}
__device__ __forceinline__ float ld_f(const void* p, int isbf, long long i) {
  return isbf ? bfbits2f(((const unsigned short*)p)[i]) : ((const float*)p)[i];
}

// Probe dtypes, transpose W (blocks<96), zero ELL (grid-stride).
__global__ void setup_kernel(const unsigned short* __restrict__ xb,
                             const unsigned* __restrict__ eiw,
                             const void* __restrict__ W1, const void* __restrict__ W2,
                             int* __restrict__ flags, unsigned short* __restrict__ Wt1,
                             unsigned short* __restrict__ Wt2, uint4* __restrict__ ellz,
                             int nell4) {
  const int tid = threadIdx.x;
  const int gid = blockIdx.x * 256 + tid;
  __shared__ int sflags[2];
  if (tid < 64) {
    unsigned short xs = xb[2 * tid];
    unsigned long long mb = __ballot(((xs >> 7) & 0xFFu) >= 0xC0u);
    unsigned long long m2 = __ballot(eiw[2 * tid + 1] != 0u);
    if (tid == 0) {
      sflags[0] = (mb == 0ull);  // no huge exponents => bf16
      sflags[1] = (m2 == 0ull);  // high words all zero => int64
      if (blockIdx.x == 0) { flags[0] = sflags[0]; flags[1] = sflags[1]; }
    }
  }
  __syncthreads();
  int f = sflags[0];
  if (blockIdx.x < 96) {
    int i = gid;  // 0..24575 == 128*128 + 128*64
    if (i < 128 * 128) {
      int k = i >> 7, nn = i & 127;
      Wt1[nn * 128 + k] = f2bfbits(ld_f(W1, f, i));
    } else {
      int j = i - 128 * 128;
      int k = j >> 6, nn = j & 63;
      Wt2[nn * 128 + k] = f2bfbits(ld_f(W2, f, j));
    }
  }
  uint4 z = make_uint4(0u, 0u, 0u, 0u);
  for (int j = gid; j < nell4; j += gridDim.x * 256) ellz[j] = z;
}

// Claim hash slots: slot = (wbits<<32)|src, empty = 0; linear-probe CAS.
__global__ void fill_ell(const void* __restrict__ ei, const void* __restrict__ ew,
                         const int* __restrict__ flg, unsigned long long* __restrict__ ell,
                         int E, int half) {
  int g = blockIdx.x * 256 + threadIdx.x;
  if (g >= half) return;
  int is64 = flg[1], isbf = flg[0];
  int sA = ld_idx(ei, is64, g);
  int dA = ld_idx(ei, is64, (long long)E + g);
  unsigned wA = f2wbits(ld_f(ew, isbf, g));
  int eB = g + half;
  bool hasB = eB < E;
  int sB = 0, dB = 0;
  unsigned wB = 0u;
  if (hasB) {
    sB = ld_idx(ei, is64, eB);
    dB = ld_idx(ei, is64, (long long)E + eB);
    wB = f2wbits(ld_f(ew, isbf, eB));
  }
  unsigned long long vA = ((unsigned long long)wA << 32) | (unsigned)sA;
  unsigned long long vB = ((unsigned long long)wB << 32) | (unsigned)sB;
  unsigned long long* rowA = ell + (size_t)dA * CAP;
  unsigned long long* rowB = ell + (size_t)dB * CAP;
  int pA = g & (CAP - 1), pB = eB & (CAP - 1);
  bool doneA = (vA == 0ull);
  bool doneB = !hasB || (vB == 0ull);
  unsigned long long oA = doneA ? 0ull : atomicCAS(&rowA[pA], 0ull, vA);
  unsigned long long oB = doneB ? 0ull : atomicCAS(&rowB[pB], 0ull, vB);
  for (int t = 1; t < CAP && !doneA && oA != 0ull; ++t) {
    pA = (pA + 1) & (CAP - 1);
    oA = atomicCAS(&rowA[pA], 0ull, vA);
  }
  for (int t = 1; t < CAP && !doneB && oB != 0ull; ++t) {
    pB = (pB + 1) & (CAP - 1);
    oB = atomicCAS(&rowB[pB], 0ull, vB);
  }
}

// Wave per node: dinv = rsqrt(1 + sum slot weights); ballot-compact valid slots
// into 4B entries (src u16 << 16 | w bf16) in place over the row's first 256B.
__global__ void dinv_compact(uint2* __restrict__ ell, float* __restrict__ dinv,
                             unsigned* __restrict__ cedge, int n) {
  int wid = (blockIdx.x * 256 + threadIdx.x) >> 6;
  int lane = threadIdx.x & 63;
  if (wid >= n) return;
  u32x2 rv = __builtin_nontemporal_load((const u32x2*)(ell + (size_t)wid * CAP) + lane);
  float w = wbits2f(rv.y);
  float ws = w;
#pragma unroll
  for (int off = 1; off < 64; off <<= 1) ws += __shfl_xor(ws, off);
  bool valid = rv.y != 0u;
  unsigned long long m = __ballot(valid);
  int c = __popcll(m);
  int rank = __popcll(m & ((1ull << lane) - 1ull));
  int destl = valid ? rank : c + (lane - rank);
  unsigned entry = valid ? ((rv.x << 16) | (unsigned)f2bfbits(w)) : 0u;
  int pe = __builtin_amdgcn_ds_permute(destl << 2, (int)entry);
  cedge[(size_t)wid * (CAP * 2) + lane] = (unsigned)pe;
  if (lane == 0) dinv[wid] = rsqrtf(1.f + ws);
}

// agg1[n,:] = dinv[n]*sum_e (w*dinv[src])*x[src_e] + dinv[n]^2*x[n]; bf16 out.
// Wave per node, single full-row pass (at the measured random-gather floor).
__launch_bounds__(256)
__global__ void gather_l1(const void* __restrict__ x, const int* __restrict__ flg,
                          const unsigned* __restrict__ cedge, const float* __restrict__ dinv,
                          unsigned* __restrict__ agg, int n) {
  int wid = (blockIdx.x * 256 + threadIdx.x) >> 6;
  int lane = threadIdx.x & 63;
  if (wid >= n) return;
  unsigned e = __builtin_nontemporal_load(cedge + (size_t)wid * (CAP * 2) + lane);
  unsigned long long m = __ballot(e != 0u);
  int c = __popcll(m);
  int rsrc = (int)(e >> 16);
  float rw = (lane < c) ? bfbits2f((unsigned short)(e & 0xFFFFu)) * dinv[rsrc] : 0.f;
  float di = dinv[wid];

  if (flg[0]) {
    const uint4* xv = (const uint4*)x;  // 16 uint4 (8 bf16 each) per 256B row
    const int fgrp = lane & 15, egrp = lane >> 4;
    float acc[8];
#pragma unroll
    for (int k = 0; k < 8; ++k) acc[k] = 0.f;
    int iters = (c + 15) >> 4;
    for (int it = 0; it < iters; ++it) {
      int b = it * 16 + egrp;
      int i0 = b, i1 = b + 4, i2 = b + 8, i3 = b + 12;
      int s0 = __shfl(rsrc, i0), s1 = __shfl(rsrc, i1);
      int s2 = __shfl(rsrc, i2), s3 = __shfl(rsrc, i3);
      float w0 = __shfl(rw, i0), w1 = __shfl(rw, i1);
      float w2 = __shfl(rw, i2), w3 = __shfl(rw, i3);
      s0 = i0 < c ? s0 : wid;
      s1 = i1 < c ? s1 : wid;
      s2 = i2 < c ? s2 : wid;
      s3 = i3 < c ? s3 : wid;
      uint4 u0 = xv[(size_t)s0 * 16 + fgrp];
      uint4 u1 = xv[(size_t)s1 * 16 + fgrp];
      uint4 u2 = xv[(size_t)s2 * 16 + fgrp];
      uint4 u3 = xv[(size_t)s3 * 16 + fgrp];
      float l, h;
      unpack_bf2(u0.x, l, h); acc[0] = fmaf(w0, l, acc[0]); acc[1] = fmaf(w0, h, acc[1]);
      unpack_bf2(u0.y, l, h); acc[2] = fmaf(w0, l, acc[2]); acc[3] = fmaf(w0, h, acc[3]);
      unpack_bf2(u0.z, l, h); acc[4] = fmaf(w0, l, acc[4]); acc[5] = fmaf(w0, h, acc[5]);
      unpack_bf2(u0.w, l, h); acc[6] = fmaf(w0, l, acc[6]); acc[7] = fmaf(w0, h, acc[7]);
      unpack_bf2(u1.x, l, h); acc[0] = fmaf(w1, l, acc[0]); acc[1] = fmaf(w1, h, acc[1]);
      unpack_bf2(u1.y, l, h); acc[2] = fmaf(w1, l, acc[2]); acc[3] = fmaf(w1, h, acc[3]);
      unpack_bf2(u1.z, l, h); acc[4] = fmaf(w1, l, acc[4]); acc[5] = fmaf(w1, h, acc[5]);
      unpack_bf2(u1.w, l, h); acc[6] = fmaf(w1, l, acc[6]); acc[7] = fmaf(w1, h, acc[7]);
      unpack_bf2(u2.x, l, h); acc[0] = fmaf(w2, l, acc[0]); acc[1] = fmaf(w2, h, acc[1]);
      unpack_bf2(u2.y, l, h); acc[2] = fmaf(w2, l, acc[2]); acc[3] = fmaf(w2, h, acc[3]);
      unpack_bf2(u2.z, l, h); acc[4] = fmaf(w2, l, acc[4]); acc[5] = fmaf(w2, h, acc[5]);
      unpack_bf2(u2.w, l, h); acc[6] = fmaf(w2, l, acc[6]); acc[7] = fmaf(w2, h, acc[7]);
      unpack_bf2(u3.x, l, h); acc[0] = fmaf(w3, l, acc[0]); acc[1] = fmaf(w3, h, acc[1]);
      unpack_bf2(u3.y, l, h); acc[2] = fmaf(w3, l, acc[2]); acc[3] = fmaf(w3, h, acc[3]);
      unpack_bf2(u3.z, l, h); acc[4] = fmaf(w3, l, acc[4]); acc[5] = fmaf(w3, h, acc[5]);
      unpack_bf2(u3.w, l, h); acc[6] = fmaf(w3, l, acc[6]); acc[7] = fmaf(w3, h, acc[7]);
    }
#pragma unroll
    for (int k = 0; k < 8; ++k) {
      acc[k] += __shfl_xor(acc[k], 16);
      acc[k] += __shfl_xor(acc[k], 32);
    }
    if (lane < 16) {
      uint4 su = xv[(size_t)wid * 16 + fgrp];
      float s0, s1, s2, s3, s4, s5, s6, s7;
      unpack_bf2(su.x, s0, s1); unpack_bf2(su.y, s2, s3);
      unpack_bf2(su.z, s4, s5); unpack_bf2(su.w, s6, s7);
      float dd = di * di;
      float o0 = di * acc[0] + dd * s0, o1 = di * acc[1] + dd * s1;
      float o2 = di * acc[2] + dd * s2, o3 = di * acc[3] + dd * s3;
      float o4 = di * acc[4] + dd * s4, o5 = di * acc[5] + dd * s5;
      float o6 = di * acc[6] + dd * s6, o7 = di * acc[7] + dd * s7;
      u32x4 pk;
      pk.x = (unsigned)f2bfbits(o0) | ((unsigned)f2bfbits(o1) << 16);
      pk.y = (unsigned)f2bfbits(o2) | ((unsigned)f2bfbits(o3) << 16);
      pk.z = (unsigned)f2bfbits(o4) | ((unsigned)f2bfbits(o5) << 16);
      pk.w = (unsigned)f2bfbits(o6) | ((unsigned)f2bfbits(o7) << 16);
      __builtin_nontemporal_store(pk, (u32x4*)agg + (size_t)wid * 16 + fgrp);
    }
  } else {
    const float4* xf = (const float4*)x;  // 32 float4 per row
    const int fgrp = lane & 31, egrp = lane >> 5;
    float acc[4] = {0.f, 0.f, 0.f, 0.f};
    int it8 = (c + 7) >> 3;
    for (int it = 0; it < it8; ++it) {
      int b = it * 8 + egrp;
#pragma unroll
      for (int t = 0; t < 4; ++t) {
        int idx = b + t * 2;
        int s = __shfl(rsrc, idx);
        float w = __shfl(rw, idx);
        s = idx < c ? s : wid;
        float4 v = xf[(size_t)s * 32 + fgrp];
        acc[0] = fmaf(w, v.x, acc[0]); acc[1] = fmaf(w, v.y, acc[1]);
        acc[2] = fmaf(w, v.z, acc[2]); acc[3] = fmaf(w, v.w, acc[3]);
      }
    }
#pragma unroll
    for (int k = 0; k < 4; ++k) acc[k] += __shfl_xor(acc[k], 32);
    if (lane < 32) {
      float4 sv = xf[(size_t)wid * 32 + fgrp];
      float dd = di * di;
      float o0 = di * acc[0] + dd * sv.x, o1 = di * acc[1] + dd * sv.y;
      float o2 = di * acc[2] + dd * sv.z, o3 = di * acc[3] + dd * sv.w;
      uint2 pk;
      pk.x = (unsigned)f2bfbits(o0) | ((unsigned)f2bfbits(o1) << 16);
      pk.y = (unsigned)f2bfbits(o2) | ((unsigned)f2bfbits(o3) << 16);
      ((uint2*)agg)[(size_t)wid * 32 + fgrp] = pk;
    }
  }
}

// Layer-2 gather, SRC-SHARDED over two launches. PASS 0: edges with
// src < half -> pacc[n][64] (f32, raw partial sum). PASS 1: edges with
// src >= half; out = di*(pacc + S1) + di^2*self + b2. f32 input: PASS 0
// no-ops, PASS 1 runs full range without pacc.
template <int PASS>
__launch_bounds__(256)
__global__ void gather_l2(const unsigned short* __restrict__ hw2, const int* __restrict__ flg,
                          const unsigned* __restrict__ cedge, const float* __restrict__ dinv,
                          const void* __restrict__ b2, float* __restrict__ pacc,
                          void* __restrict__ out, int n, int half) {
  int wid = (blockIdx.x * 256 + threadIdx.x) >> 6;
  int lane = threadIdx.x & 63;
  if (wid >= n) return;
  const int isbf = flg[0];
  if (PASS == 0 && !isbf) return;
  const int lo = (PASS == 0) ? 0 : (isbf ? half : 0);
  const int hi = (PASS == 0) ? half : n;

  unsigned e = __builtin_nontemporal_load(cedge + (size_t)wid * (CAP * 2) + lane);
  unsigned long long mv = __ballot(e != 0u);
  int call = __popcll(mv);
  int src0 = (int)(e >> 16);
  bool act = (lane < call) && src0 >= lo && src0 < hi;
  unsigned long long m = __ballot(act);
  int c = __popcll(m);
  int rank = __popcll(m & ((1ull << lane) - 1ull));
  int destl = act ? rank : c + (lane - rank);
  int pe = __builtin_amdgcn_ds_permute(destl << 2, (int)e);
  int rsrc = (lane < c) ? ((unsigned)pe >> 16) : wid;
  float rw = (lane < c) ? bfbits2f((unsigned short)((unsigned)pe & 0xFFFFu)) * dinv[rsrc] : 0.f;
  float di = dinv[wid];

  const uint4* hv = (const uint4*)hw2;  // 8 uint4 per 128B row
  const int fgrp = lane & 7, egrp = lane >> 3;
  float acc[8];
#pragma unroll
  for (int k = 0; k < 8; ++k) acc[k] = 0.f;
  int iters = (c + 15) >> 4;
  for (int it = 0; it < iters; ++it) {
    int i0 = it * 16 + egrp, i1 = i0 + 8;
    int s0 = __shfl(rsrc, i0), s1 = __shfl(rsrc, i1);
    float w0 = __shfl(rw, i0), w1 = __shfl(rw, i1);
    s0 = i0 < c ? s0 : wid;
    s1 = i1 < c ? s1 : wid;
    uint4 u0 = hv[(size_t)s0 * 8 + fgrp];
    uint4 u1 = hv[(size_t)s1 * 8 + fgrp];
    float l, h;
    unpack_bf2(u0.x, l, h); acc[0] = fmaf(w0, l, acc[0]); acc[1] = fmaf(w0, h, acc[1]);
    unpack_bf2(u0.y, l, h); acc[2] = fmaf(w0, l, acc[2]); acc[3] = fmaf(w0, h, acc[3]);
    unpack_bf2(u0.z, l, h); acc[4] = fmaf(w0, l, acc[4]); acc[5] = fmaf(w0, h, acc[5]);
    unpack_bf2(u0.w, l, h); acc[6] = fmaf(w0, l, acc[6]); acc[7] = fmaf(w0, h, acc[7]);
    unpack_bf2(u1.x, l, h); acc[0] = fmaf(w1, l, acc[0]); acc[1] = fmaf(w1, h, acc[1]);
    unpack_bf2(u1.y, l, h); acc[2] = fmaf(w1, l, acc[2]); acc[3] = fmaf(w1, h, acc[3]);
    unpack_bf2(u1.z, l, h); acc[4] = fmaf(w1, l, acc[4]); acc[5] = fmaf(w1, h, acc[5]);
    unpack_bf2(u1.w, l, h); acc[6] = fmaf(w1, l, acc[6]); acc[7] = fmaf(w1, h, acc[7]);
  }
#pragma unroll
  for (int k = 0; k < 8; ++k) {
    acc[k] += __shfl_xor(acc[k], 8);
    acc[k] += __shfl_xor(acc[k], 16);
    acc[k] += __shfl_xor(acc[k], 32);
  }
  if (lane < 8) {
    if (PASS == 0) {
      // store raw partial sum S0
      ((float4*)pacc)[(size_t)wid * 16 + fgrp * 2 + 0] =
          make_float4(acc[0], acc[1], acc[2], acc[3]);
      ((float4*)pacc)[(size_t)wid * 16 + fgrp * 2 + 1] =
          make_float4(acc[4], acc[5], acc[6], acc[7]);
    } else {
      if (isbf) {
        float4 pa = ((const float4*)pacc)[(size_t)wid * 16 + fgrp * 2 + 0];
        float4 pb = ((const float4*)pacc)[(size_t)wid * 16 + fgrp * 2 + 1];
        acc[0] += pa.x; acc[1] += pa.y; acc[2] += pa.z; acc[3] += pa.w;
        acc[4] += pb.x; acc[5] += pb.y; acc[6] += pb.z; acc[7] += pb.w;
      }
      uint4 su = hv[(size_t)wid * 8 + fgrp];
      float s0, s1, s2, s3, s4, s5, s6, s7;
      unpack_bf2(su.x, s0, s1); unpack_bf2(su.y, s2, s3);
      unpack_bf2(su.z, s4, s5); unpack_bf2(su.w, s6, s7);
      float dd = di * di;
      float o0 = di * acc[0] + dd * s0 + ld_f(b2, isbf, fgrp * 8 + 0);
      float o1 = di * acc[1] + dd * s1 + ld_f(b2, isbf, fgrp * 8 + 1);
      float o2 = di * acc[2] + dd * s2 + ld_f(b2, isbf, fgrp * 8 + 2);
      float o3 = di * acc[3] + dd * s3 + ld_f(b2, isbf, fgrp * 8 + 3);
      float o4 = di * acc[4] + dd * s4 + ld_f(b2, isbf, fgrp * 8 + 4);
      float o5 = di * acc[5] + dd * s5 + ld_f(b2, isbf, fgrp * 8 + 5);
      float o6 = di * acc[6] + dd * s6 + ld_f(b2, isbf, fgrp * 8 + 6);
      float o7 = di * acc[7] + dd * s7 + ld_f(b2, isbf, fgrp * 8 + 7);
      if (isbf) {
        uint4 pk;
        pk.x = (unsigned)f2bfbits(o0) | ((unsigned)f2bfbits(o1) << 16);
        pk.y = (unsigned)f2bfbits(o2) | ((unsigned)f2bfbits(o3) << 16);
        pk.z = (unsigned)f2bfbits(o4) | ((unsigned)f2bfbits(o5) << 16);
        pk.w = (unsigned)f2bfbits(o6) | ((unsigned)f2bfbits(o7) << 16);
        ((uint4*)out)[(size_t)wid * 8 + fgrp] = pk;
      } else {
        ((float4*)out)[(size_t)wid * 16 + fgrp * 2 + 0] = make_float4(o0, o1, o2, o3);
        ((float4*)out)[(size_t)wid * 16 + fgrp * 2 + 1] = make_float4(o4, o5, o6, o7);
      }
    }
  }
}

// Fused: H1 = relu(agg1 @ W1 + b1) [LDS only]; hw2 = H1 @ W2 [global bf16].
__launch_bounds__(256)
__global__ void gemm12(const unsigned short* __restrict__ agg1,
                       const unsigned short* __restrict__ Wt1,
                       const unsigned short* __restrict__ Wt2,
                       const void* __restrict__ b1, const int* __restrict__ flg,
                       unsigned short* __restrict__ hw2, int M) {
  __shared__ unsigned short As[128 * 128];
  __shared__ unsigned short W1s[128 * 128];
  __shared__ unsigned short W2s[64 * 128];
  const int tid = threadIdx.x;
  const int r0 = blockIdx.x * 128;

  for (int i = tid; i < 128 * 16; i += 256) {
    int r = i >> 4, ch = i & 15;
    uint4 v = make_uint4(0u, 0u, 0u, 0u);
    if (r0 + r < M) v = *(const uint4*)(agg1 + (size_t)(r0 + r) * 128 + ch * 8);
    *(uint4*)&As[r * 128 + ((ch ^ (r & 15)) << 3)] = v;
  }
  for (int i = tid; i < 128 * 16; i += 256) {
    int r = i >> 4, ch = i & 15;
    uint4 v = *(const uint4*)(Wt1 + (size_t)r * 128 + ch * 8);
    *(uint4*)&W1s[r * 128 + ((ch ^ (r & 15)) << 3)] = v;
  }
  for (int i = tid; i < 64 * 16; i += 256) {
    int r = i >> 4, ch = i & 15;
    uint4 v = *(const uint4*)(Wt2 + (size_t)r * 128 + ch * 8);
    *(uint4*)&W2s[r * 128 + ((ch ^ (r & 15)) << 3)] = v;
  }
  __syncthreads();

  const int lane = tid & 63;
  const int wv = tid >> 6;
  const int ln15 = lane & 15;
  const int kq = lane >> 4;
  const int wbf = flg[0];

  f32x4 acc1[2][8];
#pragma unroll
  for (int mi = 0; mi < 2; ++mi)
#pragma unroll
    for (int nt = 0; nt < 8; ++nt) acc1[mi][nt] = (f32x4){0.f, 0.f, 0.f, 0.f};
#pragma unroll
  for (int kc = 0; kc < 4; ++kc) {
    int coff = (((kc * 4 + kq) ^ ln15) << 3);
    bf16x8 a0 = *(const bf16x8*)&As[((2 * wv + 0) * 16 + ln15) * 128 + coff];
    bf16x8 a1 = *(const bf16x8*)&As[((2 * wv + 1) * 16 + ln15) * 128 + coff];
#pragma unroll
    for (int nt = 0; nt < 8; ++nt) {
      bf16x8 b = *(const bf16x8*)&W1s[(nt * 16 + ln15) * 128 + coff];
      acc1[0][nt] = __builtin_amdgcn_mfma_f32_16x16x32_bf16(a0, b, acc1[0][nt], 0, 0, 0);
      acc1[1][nt] = __builtin_amdgcn_mfma_f32_16x16x32_bf16(a1, b, acc1[1][nt], 0, 0, 0);
    }
  }

#pragma unroll
  for (int nt = 0; nt < 8; ++nt) {
    int col = nt * 16 + ln15;
    float bv = ld_f(b1, wbf, col);
#pragma unroll
    for (int mi = 0; mi < 2; ++mi) {
#pragma unroll
      for (int r = 0; r < 4; ++r) {
        int row = 32 * wv + mi * 16 + kq * 4 + r;
        float o = fmaxf(acc1[mi][nt][r] + bv, 0.f);
        As[row * 128 + ((((col >> 3)) ^ (row & 15)) << 3) + (col & 7)] = f2bfbits(o);
      }
    }
  }
  __syncthreads();

  f32x4 acc2[2][4];
#pragma unroll
  for (int mi = 0; mi < 2; ++mi)
#pragma unroll
    for (int nt = 0; nt < 4; ++nt) acc2[mi][nt] = (f32x4){0.f, 0.f, 0.f, 0.f};
#pragma unroll
  for (int kc = 0; kc < 4; ++kc) {
    int coff = (((kc * 4 + kq) ^ ln15) << 3);
    bf16x8 a0 = *(const bf16x8*)&As[((2 * wv + 0) * 16 + ln15) * 128 + coff];
    bf16x8 a1 = *(const bf16x8*)&As[((2 * wv + 1) * 16 + ln15) * 128 + coff];
#pragma unroll
    for (int nt = 0; nt < 4; ++nt) {
      bf16x8 b = *(const bf16x8*)&W2s[(nt * 16 + ln15) * 128 + coff];
      acc2[0][nt] = __builtin_amdgcn_mfma_f32_16x16x32_bf16(a0, b, acc2[0][nt], 0, 0, 0);
      acc2[1][nt] = __builtin_amdgcn_mfma_f32_16x16x32_bf16(a1, b, acc2[1][nt], 0, 0, 0);
    }
  }
#pragma unroll
  for (int nt = 0; nt < 4; ++nt) {
    int col = nt * 16 + ln15;
#pragma unroll
    for (int mi = 0; mi < 2; ++mi) {
#pragma unroll
      for (int r = 0; r < 4; ++r) {
        int gr = r0 + 32 * wv + mi * 16 + kq * 4 + r;
        if (gr < M) hw2[(size_t)gr * 64 + col] = f2bfbits(acc2[mi][nt][r]);
      }
    }
  }
}

extern "C" void kernel_launch(void* const* d_in, const int* in_sizes, int n_in, void* d_out,
                              int out_size, void* d_ws, size_t ws_size, hipStream_t stream) {
  const void* x  = d_in[0];
  const void* ei = d_in[1];
  const void* ew = d_in[2];
  const void* W1 = d_in[3];
  const void* b1 = d_in[4];
  const void* W2 = d_in[5];
  const void* b2 = d_in[6];

  const int N = in_sizes[0] / FIN;  // 50000
  const int E = in_sizes[1] / 2;    // 800000
  const int B = 256;

  // ws: flags[16]i | dinv[N]f | Wt1 | Wt2 | ell[N*CAP]u64 (cedge in first 256B
  // of each row) | agg1[N*128]bf (reused as f32 pacc[N*64] by gather_l2 after
  // gemm12 consumes it) | hw2[N*64]bf   (~45.1 MB)
  int* flags   = (int*)d_ws;
  float* dinv  = (float*)(flags + 16);
  unsigned short* Wt1 = (unsigned short*)(dinv + N);
  unsigned short* Wt2 = Wt1 + 128 * 128;
  unsigned long long* ell = (unsigned long long*)(Wt2 + 64 * 128);
  unsigned* cedge = (unsigned*)ell;
  unsigned short* agg1 = (unsigned short*)(ell + (size_t)N * CAP);
  unsigned short* hw2  = agg1 + (size_t)N * FHID;
  float* pacc = (float*)agg1;  // N*64 f32 == N*128 bf16 bytes; agg1 dead post-gemm12

  const int half = (E + 1) / 2;
  const int nhalf = N / 2;  // src shard boundary (25000)
  setup_kernel<<<512, B, 0, stream>>>((const unsigned short*)x, (const unsigned*)ei, W1, W2,
                                      flags, Wt1, Wt2, (uint4*)ell, N * CAP / 2);
  fill_ell<<<(half + B - 1) / B, B, 0, stream>>>(ei, ew, flags, ell, E, half);
  dinv_compact<<<(N + 3) / 4, B, 0, stream>>>((uint2*)ell, dinv, cedge, N);
  gather_l1<<<(N + 3) / 4, B, 0, stream>>>(x, flags, cedge, dinv, (unsigned*)agg1, N);
  gemm12<<<(N + 127) / 128, B, 0, stream>>>(agg1, Wt1, Wt2, b1, flags, hw2, N);
  gather_l2<0><<<(N + 3) / 4, B, 0, stream>>>(hw2, flags, cedge, dinv, b2, pacc, d_out, N,
                                              nhalf);
  gather_l2<1><<<(N + 3) / 4, B, 0, stream>>>(hw2, flags, cedge, dinv, b2, pacc, d_out, N,
                                              nhalf);
}